// Round 1
// baseline (812.161 us; speedup 1.0000x reference)
//
#include <hip/hip_runtime.h>
#include <hip/hip_bf16.h>
#include <cstdint>

// Problem constants
#define B_     2
#define N_     100000
#define C_     256
#define H_     8
#define D_     64
#define S_     64
#define INNER_ 512

#define TILE_T 64
#define NTILES ((N_ + TILE_T - 1) / TILE_T)   // 1563
#define PBLK   32                             // blocks per (b,h); grid = 32*8*2 = 512 blocks of 512 thr

// Workspace layout (bytes) — identical to v4
#define WEFFT_OFF 0                           // bf16 [H][S][C]   = 262144  (pre-scaled by log2e/temp)
#define WFXT_OFF  262144                      // bf16 [H][D][C]   = 262144
#define BIASE_OFF 524288                      // f32  [H][S]      = 2048    (pre-scaled)
#define SLAB_OFF  526336                      // f32 [B*H][PBLK][4096] = 8388608
#define NSLAB_OFF (SLAB_OFF + B_*H_*PBLK*4096*4)
#define WS_BIG_END (NSLAB_OFF + B_*H_*PBLK*64*4)   // ~9.05 MB
#define ACC_OFF   526336
#define NRM_OFF   (ACC_OFF + B_*H_*S_*D_*4)
#define WS_SMALL_END (NRM_OFF + B_*H_*S_*4)

typedef __attribute__((ext_vector_type(8)))  short short8;
typedef __attribute__((ext_vector_type(4)))  float f32x4;
typedef __attribute__((ext_vector_type(16))) float f32x16;

__device__ inline short f2bf(float f) {
    __hip_bfloat16 h = __float2bfloat16(f);
    short s; __builtin_memcpy(&s, &h, 2); return s;
}
__device__ inline uint32_t pk2(float a, float b) {
    __hip_bfloat162 h = __float22bfloat162_rn(float2{a, b});
    uint32_t u; __builtin_memcpy(&u, &h, 4); return u;
}

// ---------------------------------------------------------------------------
// prep: unchanged from v4.
//   weffT[h][s][k] = (sum_d W_x[k][h*64+d]*W_slice[d][s]) * log2e/temp_h   (bf16)
//   wfxT[h][d][k]  = W_fx[k][h*64+d]                                       (bf16)
//   biasE[h][s]    = (sum_d b_x*W_slice + b_slice[s]) * log2e/temp_h       (f32)
// ---------------------------------------------------------------------------
__global__ void prep_kernel(const float* __restrict__ W_x,
                            const float* __restrict__ b_x,
                            const float* __restrict__ W_fx,
                            const float* __restrict__ W_slice,
                            const float* __restrict__ b_slice,
                            const float* __restrict__ temperature,
                            uint8_t* __restrict__ wsb) {
    int wid  = (blockIdx.x * 256 + threadIdx.x) >> 6;
    int lane = threadIdx.x & 63;
    if (wid < H_ * C_) {
        int h = wid >> 8, k = wid & 255;
        float t = temperature[h]; t = fminf(fmaxf(t, 0.1f), 5.0f);
        float sc = 1.44269504088896f / t;
        const float* wx = W_x + k * INNER_ + h * 64;
        float a = 0.f;
        #pragma unroll 8
        for (int d = 0; d < D_; ++d)
            a = fmaf(wx[d], W_slice[d * 64 + lane], a);
        ((short*)(wsb + WEFFT_OFF))[(h * 64 + lane) * 256 + k] = f2bf(a * sc);
    } else if (wid < 2 * H_ * C_) {
        int j = wid - H_ * C_;
        int h = j >> 8, k = j & 255;
        ((short*)(wsb + WFXT_OFF))[(h * 64 + lane) * 256 + k] =
            f2bf(W_fx[k * INNER_ + h * 64 + lane]);
    } else if (wid < 2 * H_ * C_ + H_) {
        int h = wid - 2 * H_ * C_;
        float t = temperature[h]; t = fminf(fmaxf(t, 0.1f), 5.0f);
        float sc = 1.44269504088896f / t;
        float a = 0.f;
        #pragma unroll 8
        for (int d = 0; d < D_; ++d)
            a = fmaf(b_x[h * 64 + d], W_slice[d * 64 + lane], a);
        ((float*)(wsb + BIASE_OFF))[h * 64 + lane] = (a + b_slice[lane]) * sc;
    }
}

// ---------------------------------------------------------------------------
// main v5: 32x32x16 MFMA everywhere (2x FLOP per LDS A-byte vs 16x16x32).
// Roles (8 waves): main GEMM wave = (g = wv>>2, mh = (wv>>1)&1, nh = wv&1):
//   g=0 logits / g=1 fx; 32-token half mh; 32-col half nh.
//   breg = 16 k-frags (64 VGPR) persistent; A-frags from LDS (16 reads/tile,
//   half of v4's per-wave traffic).
// C-layout of 32x32 (col=lane&31, row=(r&3)+8*(r>>2)+4*(lane>>5)) writes the
// overlays COLUMN-MAJOR: wsl[s][tok], fsl[d][tok] -> both agg fragments are
// contiguous ds_read_b128 (A = w^T wants [s][tok-contig], B = fx wants
// [d][tok-contig]).
// Agg wave = (kh = wv>>2 token-half, sh = (wv>>1)&1, dh = wv&1); kh partial
// sums combined once at kernel end through LDS (xs region reused).
// Barriers per tile: 3 (xs un-unioned from wsl/fsl kills v4's B1).
// ---------------------------------------------------------------------------
template<bool SLAB>
__global__ __launch_bounds__(512, 2) void main_kernel(
        const float* __restrict__ x,
        const float* __restrict__ b_fx,
        const uint8_t* __restrict__ wsb,
        float* __restrict__ accg,
        float* __restrict__ nrmg) {
    __shared__ union {
        short xs[TILE_T * 264];                         // 33792 B
        struct { float eg[4][64][16]; float np[4][64]; } fin;  // 17408 B (endgame)
    } u;
    __shared__ short wsl[S_ * 72];                      // 9216 B  [s][tok] bf16
    __shared__ short fsl[D_ * 72];                      // 9216 B  [d][tok] bf16
    __shared__ float smB[TILE_T * 2];                   // 512 B   [tok][nh] partial sumexp

    const int tid = threadIdx.x;
    const int bid = blockIdx.x;
    // XCD swizzle: 8 h-siblings of each (p,b) share bid%8 (same XCD L2)
    const int cc = bid & 7;
    const int h  = (bid >> 3) & 7;
    const int pb = (bid >> 6) * 8 + cc;
    const int p  = pb & 31;
    const int b  = pb >> 5;

    const int lane = tid & 63, wv = tid >> 6;
    const int l31 = lane & 31, hh = lane >> 5;
    const int g  = wv >> 2;                   // 0: logits, 1: fx
    const int mh = (wv >> 1) & 1;             // token half (main)
    const int nh = wv & 1;                    // col half (main)
    const int kh = g, sh = mh, dh = nh;       // agg roles

    // persistent B-frags: B[k][col], lane: col = l31, k = hh*8 + j within kk*16
    const short* wT = (const short*)(wsb + (g ? WFXT_OFF : WEFFT_OFF)) + h * (64 * 256);
    short8 breg[16];
    #pragma unroll
    for (int kk = 0; kk < 16; ++kk)
        breg[kk] = *(const short8*)(wT + (nh * 32 + l31) * 256 + kk * 16 + hh * 8);

    const float bias_n = g ? b_fx[h * 64 + nh * 32 + l31]
                           : ((const float*)(wsb + BIASE_OFF))[h * 64 + nh * 32 + l31];

    const float* xb = x + (size_t)b * ((size_t)N_ * C_);
    f32x16 accO = {};                         // agg accumulator (32s x 32d quarter, kh-partial)
    float nrmacc = 0.f;

    // prologue: prefetch first tile into registers
    float4 xv[8];
    {
        const int col = lane * 4;
        #pragma unroll
        for (int j = 0; j < 8; ++j) {
            int gt = p * TILE_T + wv + 8 * j;
            xv[j] = (gt < N_) ? *(const float4*)(xb + (size_t)gt * C_ + col)
                              : float4{0.f, 0.f, 0.f, 0.f};
        }
    }

    #pragma unroll 1
    for (int tile = p; tile < NTILES; tile += PBLK) {
        // ---- pack prefetched tile -> xs (bf16). Safe without extra barrier:
        // prior-iter xs reads all completed before prior B3.
        #pragma unroll
        for (int j = 0; j < 8; ++j) {
            int row = wv + 8 * j;
            uint2 pk = { pk2(xv[j].x, xv[j].y), pk2(xv[j].z, xv[j].w) };
            *(uint2*)(u.xs + row * 264 + lane * 4) = pk;
        }
        __syncthreads();                      // B2: xs ready

        // ---- issue prefetch of NEXT tile (hides under MFMA+softmax+agg)
        {
            int nxt = tile + PBLK;
            if (nxt < NTILES) {
                const int col = lane * 4;
                #pragma unroll
                for (int j = 0; j < 8; ++j) {
                    int gt = nxt * TILE_T + wv + 8 * j;
                    xv[j] = (gt < N_) ? *(const float4*)(xb + (size_t)gt * C_ + col)
                                      : float4{0.f, 0.f, 0.f, 0.f};
                }
            }
        }

        // ---- main MFMA: A = xs rows (lane: row = mh*32+l31, k = hh*8+j)
        f32x16 acc = {};
        #pragma unroll
        for (int kk = 0; kk < 16; ++kk) {
            short8 a = *(const short8*)(u.xs + (mh * 32 + l31) * 264 + kk * 16 + hh * 8);
            acc = __builtin_amdgcn_mfma_f32_32x32x16_bf16(a, breg[kk], acc, 0, 0, 0);
        }

        if (g == 0) {
            // logits pre-scaled to log2 domain: e = exp2(v + bias)
            // row-sum over this wave's 32 s-cols: xor 1..16 stays within 32-lane half
            #pragma unroll
            for (int r = 0; r < 16; ++r) {
                float e = __builtin_amdgcn_exp2f(acc[r] + bias_n);
                acc[r] = e;
                float s = e;
                s += __shfl_xor(s, 1, 64);
                s += __shfl_xor(s, 2, 64);
                s += __shfl_xor(s, 4, 64);
                s += __shfl_xor(s, 8, 64);
                s += __shfl_xor(s, 16, 64);
                if (l31 == 0)
                    smB[(mh * 32 + (r & 3) + 8 * (r >> 2) + hh * 4) * 2 + nh] = s;
            }
        } else {
            #pragma unroll
            for (int r = 0; r < 16; ++r) acc[r] += bias_n;
            // write fsl[d][tok] now (no smB dependency); read after B4
            #pragma unroll
            for (int rq = 0; rq < 4; ++rq) {
                uint2 pk = { pk2(acc[rq * 4 + 0], acc[rq * 4 + 1]),
                             pk2(acc[rq * 4 + 2], acc[rq * 4 + 3]) };
                *(uint2*)(fsl + (nh * 32 + l31) * 72 + mh * 32 + rq * 8 + hh * 4) = pk;
            }
        }
        __syncthreads();                      // B3: smB ready

        if (g == 0) {
            const int t0 = tile * TILE_T;
            #pragma unroll
            for (int rq = 0; rq < 4; ++rq) {
                const float* sB = smB + mh * 64 + rq * 16 + hh * 8;   // = tok0*2
                float4 sa = *(const float4*)sB;
                float4 sb = *(const float4*)(sB + 4);
                float Ssum[4] = { sa.x + sa.y, sa.z + sa.w, sb.x + sb.y, sb.z + sb.w };
                float w[4];
                #pragma unroll
                for (int i = 0; i < 4; ++i) {
                    float f = __builtin_amdgcn_rcpf(Ssum[i]);
                    int tok = mh * 32 + rq * 8 + hh * 4 + i;
                    if (t0 + tok >= N_) f = 0.f;
                    w[i] = acc[rq * 4 + i] * f;
                    nrmacc += w[i];
                }
                uint2 pk = { pk2(w[0], w[1]), pk2(w[2], w[3]) };
                *(uint2*)(wsl + (nh * 32 + l31) * 72 + mh * 32 + rq * 8 + hh * 4) = pk;
            }
        }
        __syncthreads();                      // B4: wsl/fsl ready

        // ---- agg MFMA: accO += w^T @ fx over this wave's 32-token half
        #pragma unroll
        for (int kk = 0; kk < 2; ++kk) {
            const int tB = kh * 32 + kk * 16 + hh * 8;
            short8 aw = *(const short8*)(wsl + (sh * 32 + l31) * 72 + tB);
            short8 bf = *(const short8*)(fsl + (dh * 32 + l31) * 72 + tB);
            accO = __builtin_amdgcn_mfma_f32_32x32x16_bf16(aw, bf, accO, 0, 0, 0);
        }
    }

    // ---- endgame: combine kh partials through LDS (xs region is dead),
    // combine nrm partials, write slab/atomics.
    if (kh == 1) {
        const int wi = wv - 4;
        #pragma unroll
        for (int rq = 0; rq < 4; ++rq) {
            f32x4 t = { accO[rq * 4 + 0], accO[rq * 4 + 1],
                        accO[rq * 4 + 2], accO[rq * 4 + 3] };
            *(f32x4*)&u.fin.eg[wi][lane][rq * 4] = t;
        }
    } else {
        u.fin.np[mh * 2 + hh][nh * 32 + l31] = nrmacc;
    }
    __syncthreads();
    if (kh == 0) {
        #pragma unroll
        for (int r = 0; r < 16; ++r) accO[r] += u.fin.eg[wv][lane][r];
        if (SLAB) {
            float* sp = accg + ((size_t)(b * H_ + h) * PBLK + p) * 4096;
            #pragma unroll
            for (int r = 0; r < 16; ++r)
                sp[(sh * 32 + (r & 3) + 8 * (r >> 2) + hh * 4) * 64 + dh * 32 + l31] = accO[r];
        } else {
            float* ag = accg + (size_t)((b * H_ + h) * 64) * 64;
            #pragma unroll
            for (int r = 0; r < 16; ++r)
                atomicAdd(ag + (sh * 32 + (r & 3) + 8 * (r >> 2) + hh * 4) * 64 + dh * 32 + l31,
                          accO[r]);
        }
    }
    if (wv == 0) {
        float v = u.fin.np[0][lane] + u.fin.np[1][lane]
                + u.fin.np[2][lane] + u.fin.np[3][lane];
        if (SLAB) nrmg[((b * H_ + h) * PBLK + p) * 64 + lane] = v;
        else      atomicAdd(nrmg + (b * H_ + h) * 64 + lane, v);
    }
}

// ---------------------------------------------------------------------------
__global__ void finalize_big(const float* __restrict__ slab,
                             const float* __restrict__ nslab,
                             float* __restrict__ out) {
    int idx = blockIdx.x * 256 + threadIdx.x;  // 65536
    int bh = idx >> 12, sd = idx & 4095, s = sd >> 6;
    const float* sp = slab  + (size_t)bh * PBLK * 4096 + sd;
    const float* np = nslab + bh * PBLK * 64 + s;
    float acc = 0.f, nn = 0.f;
    #pragma unroll 8
    for (int p = 0; p < PBLK; ++p) { acc += sp[p * 4096]; nn += np[p * 64]; }
    out[idx] = acc / (nn + 1e-5f);
}

__global__ void finalize_small(const uint8_t* __restrict__ wsb, float* __restrict__ out) {
    int idx = blockIdx.x * 256 + threadIdx.x;
    float a = ((const float*)(wsb + ACC_OFF))[idx];
    float n = ((const float*)(wsb + NRM_OFF))[idx / D_];
    out[idx] = a / (n + 1e-5f);
}

// ---------------------------------------------------------------------------
extern "C" void kernel_launch(void* const* d_in, const int* in_sizes, int n_in,
                              void* d_out, int out_size, void* d_ws, size_t ws_size,
                              hipStream_t stream) {
    const float* x           = (const float*)d_in[0];
    const float* W_x         = (const float*)d_in[1];
    const float* b_x         = (const float*)d_in[2];
    const float* W_fx        = (const float*)d_in[3];
    const float* b_fx        = (const float*)d_in[4];
    const float* W_slice     = (const float*)d_in[5];
    const float* b_slice     = (const float*)d_in[6];
    const float* temperature = (const float*)d_in[7];
    float* out = (float*)d_out;
    uint8_t* wsb = (uint8_t*)d_ws;

    int prep_waves = 2 * H_ * C_ + H_;                 // 4104
    prep_kernel<<<dim3((prep_waves + 3) / 4), dim3(256), 0, stream>>>(
        W_x, b_x, W_fx, W_slice, b_slice, temperature, wsb);

    if (ws_size >= (size_t)WS_BIG_END) {
        main_kernel<true><<<dim3(PBLK * H_ * B_), dim3(512), 0, stream>>>(
            x, b_fx, wsb, (float*)(wsb + SLAB_OFF), (float*)(wsb + NSLAB_OFF));
        finalize_big<<<dim3(256), dim3(256), 0, stream>>>(
            (const float*)(wsb + SLAB_OFF), (const float*)(wsb + NSLAB_OFF), out);
    } else {
        hipMemsetAsync(wsb + ACC_OFF, 0, (B_ * H_ * S_ * D_ + B_ * H_ * S_) * 4, stream);
        main_kernel<false><<<dim3(PBLK * H_ * B_), dim3(512), 0, stream>>>(
            x, b_fx, wsb, (float*)(wsb + ACC_OFF), (float*)(wsb + NRM_OFF));
        finalize_small<<<dim3(256), dim3(256), 0, stream>>>(wsb, out);
    }
}

// Round 3
// 768.987 us; speedup vs baseline: 1.0561x; 1.0561x over previous
//
#include <hip/hip_runtime.h>
#include <hip/hip_bf16.h>
#include <cstdint>

// Problem constants
#define B_     2
#define N_     100000
#define C_     256
#define H_     8
#define D_     64
#define S_     64
#define INNER_ 512

#define TILE_T 64
#define NTILES ((N_ + TILE_T - 1) / TILE_T)   // 1563
#define PBLK   32                             // blocks per (b,h); grid = 32*8*2 = 512 blocks of 512 thr

// Workspace layout (bytes)
#define WEFFT_OFF 0                           // bf16 [H][S][C]   = 262144  (pre-scaled by log2e/temp)
#define WFXT_OFF  262144                      // bf16 [H][D][C]   = 262144
#define BIASE_OFF 524288                      // f32  [H][S]      = 2048    (pre-scaled)
#define SLAB_OFF  526336                      // f32 [B*H][PBLK][4096] = 8388608
#define NSLAB_OFF (SLAB_OFF + B_*H_*PBLK*4096*4)
#define WS_BIG_END (NSLAB_OFF + B_*H_*PBLK*64*4)   // ~9.05 MB
#define ACC_OFF   526336
#define NRM_OFF   (ACC_OFF + B_*H_*S_*D_*4)
#define WS_SMALL_END (NRM_OFF + B_*H_*S_*4)

typedef __attribute__((ext_vector_type(8)))  short short8;
typedef __attribute__((ext_vector_type(4)))  float f32x4;

__device__ inline short f2bf(float f) {
    __hip_bfloat16 h = __float2bfloat16(f);
    short s; __builtin_memcpy(&s, &h, 2); return s;
}
__device__ inline uint32_t pk2(float a, float b) {
    __hip_bfloat162 h = __float22bfloat162_rn(float2{a, b});
    uint32_t u; __builtin_memcpy(&u, &h, 4); return u;
}

// ---------------------------------------------------------------------------
// prep: unchanged (v4).
// ---------------------------------------------------------------------------
__global__ void prep_kernel(const float* __restrict__ W_x,
                            const float* __restrict__ b_x,
                            const float* __restrict__ W_fx,
                            const float* __restrict__ W_slice,
                            const float* __restrict__ b_slice,
                            const float* __restrict__ temperature,
                            uint8_t* __restrict__ wsb) {
    int wid  = (blockIdx.x * 256 + threadIdx.x) >> 6;
    int lane = threadIdx.x & 63;
    if (wid < H_ * C_) {
        int h = wid >> 8, k = wid & 255;
        float t = temperature[h]; t = fminf(fmaxf(t, 0.1f), 5.0f);
        float sc = 1.44269504088896f / t;
        const float* wx = W_x + k * INNER_ + h * 64;
        float a = 0.f;
        #pragma unroll 8
        for (int d = 0; d < D_; ++d)
            a = fmaf(wx[d], W_slice[d * 64 + lane], a);
        ((short*)(wsb + WEFFT_OFF))[(h * 64 + lane) * 256 + k] = f2bf(a * sc);
    } else if (wid < 2 * H_ * C_) {
        int j = wid - H_ * C_;
        int h = j >> 8, k = j & 255;
        ((short*)(wsb + WFXT_OFF))[(h * 64 + lane) * 256 + k] =
            f2bf(W_fx[k * INNER_ + h * 64 + lane]);
    } else if (wid < 2 * H_ * C_ + H_) {
        int h = wid - 2 * H_ * C_;
        float t = temperature[h]; t = fminf(fmaxf(t, 0.1f), 5.0f);
        float sc = 1.44269504088896f / t;
        float a = 0.f;
        #pragma unroll 8
        for (int d = 0; d < D_; ++d)
            a = fmaf(b_x[h * 64 + d], W_slice[d * 64 + lane], a);
        ((float*)(wsb + BIASE_OFF))[h * 64 + lane] = (a + b_slice[lane]) * sc;
    }
}

// ---------------------------------------------------------------------------
// main v6.1 = v4 structure + 32x32 per-wave main-GEMM tile via 2x2 16x16x32
// MFMAs (4 independent accumulators, v4 fragment layouts preserved).
// Main roles: g = wv>>2 (0 logits / 1 fx), mh = (wv>>1)&1 (token half),
//   nh = wv&1 (32-col half). breg[2][8] persistent (64 VGPR); per-wave
//   A-reads halved vs v4 (16 x b128 per tile, each row reused for 2 cols).
// Agg roles unchanged from v4: (s-strip w4 = wv&3, d-half g).
// xs un-unioned from wsl/fsl -> B1 dropped (3 barriers/tile).
// v6.1 fix: NEXT-tile prefetch issued after B4 (not after B2), so the 32
//   in-flight xv regs never overlap the live acc[2][2] of MFMA/softmax ->
//   peak regs ~120 total, fits the (512,4)=128 cap with no spill, 2 blk/CU.
//   Loads covered by agg MFMAs + loop-back pack; x is L3-resident so
//   effective latency is L2/L3-class.
// ---------------------------------------------------------------------------
template<bool SLAB>
__global__ __launch_bounds__(512, 4) void main_kernel(
        const float* __restrict__ x,
        const float* __restrict__ b_fx,
        const uint8_t* __restrict__ wsb,
        float* __restrict__ accg,
        float* __restrict__ nrmg) {
    __shared__ union {
        short xs[TILE_T * 264];               // 33792 B  [tok][k] bf16
        float np[2][64];                      // endgame nrm combine
    } u;
    __shared__ short wsl[S_ * 72];            // 9216 B  [s][tok] bf16
    __shared__ short fsl[D_ * 72];            // 9216 B  [d][tok] bf16
    __shared__ float smB[TILE_T * 2];         // 512 B   [tok][nh] partial sumexp

    const int tid = threadIdx.x;
    const int bid = blockIdx.x;
    // XCD swizzle: 8 h-siblings of each (p,b) group share bid%8 (same XCD)
    const int cc = bid & 7;
    const int h  = (bid >> 3) & 7;
    const int pb = (bid >> 6) * 8 + cc;
    const int p  = pb & 31;
    const int b  = pb >> 5;

    const int lane = tid & 63, wv = tid >> 6;
    const int l = lane & 15, q = lane >> 4;
    const int g  = wv >> 2;                   // 0: logits, 1: fx  (also agg d-half)
    const int mh = (wv >> 1) & 1;             // main: token half
    const int nh = wv & 1;                    // main: col half
    const int w4 = wv & 3;                    // agg: s-strip

    // persistent B-frags: 2 col-groups x 8 k-frags (64 regs)
    const short* wT = (const short*)(wsb + (g ? WFXT_OFF : WEFFT_OFF)) + h * (64 * 256);
    short8 breg[2][8];
    #pragma unroll
    for (int j = 0; j < 2; ++j)
        #pragma unroll
        for (int k = 0; k < 8; ++k)
            breg[j][k] = *(const short8*)(wT + (nh * 32 + j * 16 + l) * 256 + k * 32 + q * 8);

    float bias[2];
    {
        const float* bp = g ? (b_fx + h * 64)
                            : ((const float*)(wsb + BIASE_OFF) + h * 64);
        bias[0] = bp[nh * 32 + l];
        bias[1] = bp[nh * 32 + 16 + l];
    }

    const float* xb = x + (size_t)b * ((size_t)N_ * C_);
    f32x4 accO[2] = {};                       // agg out: [16 s][32 d] strip (v4)
    float nrm0 = 0.f, nrm1 = 0.f;             // per-lane norm partials (s cols j=0/1)

    // prologue: prefetch first tile into registers
    float4 xv[8];
    {
        const int col = lane * 4;
        #pragma unroll
        for (int j = 0; j < 8; ++j) {
            int gt = p * TILE_T + wv + 8 * j;
            xv[j] = (gt < N_) ? *(const float4*)(xb + (size_t)gt * C_ + col)
                              : float4{0.f, 0.f, 0.f, 0.f};
        }
    }

    #pragma unroll 1
    for (int tile = p; tile < NTILES; tile += PBLK) {
        // ---- pack prefetched tile -> xs. Safe without a barrier: previous
        // iteration's xs reads (main MFMA) completed before previous B3/B4,
        // and agg (between B4 and here) touches only wsl/fsl.
        #pragma unroll
        for (int j = 0; j < 8; ++j) {
            int row = wv + 8 * j;
            uint2 pk = { pk2(xv[j].x, xv[j].y), pk2(xv[j].z, xv[j].w) };
            *(uint2*)(u.xs + row * 264 + lane * 4) = pk;
        }
        __syncthreads();                      // B2: xs ready

        // ---- main MFMA: 32 tok x 32 col per wave, 4 independent accumulators
        f32x4 acc[2][2] = {};
        #pragma unroll
        for (int k = 0; k < 8; ++k) {
            short8 a0 = *(const short8*)(u.xs + (mh * 32 + l) * 264 + k * 32 + q * 8);
            short8 a1 = *(const short8*)(u.xs + (mh * 32 + 16 + l) * 264 + k * 32 + q * 8);
            acc[0][0] = __builtin_amdgcn_mfma_f32_16x16x32_bf16(a0, breg[0][k], acc[0][0], 0, 0, 0);
            acc[0][1] = __builtin_amdgcn_mfma_f32_16x16x32_bf16(a0, breg[1][k], acc[0][1], 0, 0, 0);
            acc[1][0] = __builtin_amdgcn_mfma_f32_16x16x32_bf16(a1, breg[0][k], acc[1][0], 0, 0, 0);
            acc[1][1] = __builtin_amdgcn_mfma_f32_16x16x32_bf16(a1, breg[1][k], acc[1][1], 0, 0, 0);
        }

        if (g == 0) {
            // exp2 (pre-scaled log2 domain) + partial row-sum over this wave's
            // 32 s-cols (2 regs + 4-step shfl over l)
            #pragma unroll
            for (int i = 0; i < 2; ++i)
                #pragma unroll
                for (int r = 0; r < 4; ++r) {
                    float e0 = __builtin_amdgcn_exp2f(acc[i][0][r] + bias[0]);
                    float e1 = __builtin_amdgcn_exp2f(acc[i][1][r] + bias[1]);
                    acc[i][0][r] = e0;
                    acc[i][1][r] = e1;
                    float s = e0 + e1;
                    s += __shfl_xor(s, 1, 64);
                    s += __shfl_xor(s, 2, 64);
                    s += __shfl_xor(s, 4, 64);
                    s += __shfl_xor(s, 8, 64);
                    if (l == 0) smB[(mh * 32 + i * 16 + q * 4 + r) * 2 + nh] = s;
                }
        } else {
            // fx: add bias, write fsl now (no smB dependency; safe vs agg(t-1)
            // because B2 separates agg reads from these writes)
            #pragma unroll
            for (int i = 0; i < 2; ++i) {
                #pragma unroll
                for (int r = 0; r < 4; ++r) {
                    acc[i][0][r] += bias[0];
                    acc[i][1][r] += bias[1];
                }
                #pragma unroll
                for (int j = 0; j < 2; ++j) {
                    uint2 pk = { pk2(acc[i][j][0], acc[i][j][1]),
                                 pk2(acc[i][j][2], acc[i][j][3]) };
                    *(uint2*)(fsl + (nh * 32 + j * 16 + l) * 72 + mh * 32 + i * 16 + q * 4) = pk;
                }
            }
        }
        __syncthreads();                      // B3: smB (and fsl) ready

        if (g == 0) {
            const int t0 = tile * TILE_T;
            #pragma unroll
            for (int i = 0; i < 2; ++i) {
                const int tb = mh * 32 + i * 16 + q * 4;
                float4 fa = *(const float4*)(smB + tb * 2);
                float4 fb = *(const float4*)(smB + tb * 2 + 4);
                float Ss[4] = { fa.x + fa.y, fa.z + fa.w, fb.x + fb.y, fb.z + fb.w };
                float w0[4], w1[4];
                #pragma unroll
                for (int r = 0; r < 4; ++r) {
                    float f = __builtin_amdgcn_rcpf(Ss[r]);
                    if (t0 + tb + r >= N_) f = 0.f;
                    w0[r] = acc[i][0][r] * f;
                    w1[r] = acc[i][1][r] * f;
                    nrm0 += w0[r];
                    nrm1 += w1[r];
                }
                uint2 p0 = { pk2(w0[0], w0[1]), pk2(w0[2], w0[3]) };
                uint2 p1 = { pk2(w1[0], w1[1]), pk2(w1[2], w1[3]) };
                *(uint2*)(wsl + (nh * 32 + l) * 72      + tb) = p0;
                *(uint2*)(wsl + (nh * 32 + 16 + l) * 72 + tb) = p1;
            }
        }
        __syncthreads();                      // B4: wsl ready

        // ---- issue prefetch of NEXT tile here: xv regs are dead during
        // MFMA/softmax (peak-reg phases); loads hide under agg + loop-back.
        {
            int nxt = tile + PBLK;
            if (nxt < NTILES) {
                const int col = lane * 4;
                #pragma unroll
                for (int j = 0; j < 8; ++j) {
                    int gt = nxt * TILE_T + wv + 8 * j;
                    xv[j] = (gt < N_) ? *(const float4*)(xb + (size_t)gt * C_ + col)
                                      : float4{0.f, 0.f, 0.f, 0.f};
                }
            }
        }

        // ---- agg MFMA (v4 verbatim): wave = (s-strip w4, d-half g)
        #pragma unroll
        for (int kk = 0; kk < 2; ++kk) {
            short8 aw = *(const short8*)(wsl + (w4 * 16 + l) * 72 + kk * 32 + q * 8);
            #pragma unroll
            for (int nt = 0; nt < 2; ++nt) {
                short8 bf = *(const short8*)(fsl + (g * 32 + nt * 16 + l) * 72 + kk * 32 + q * 8);
                accO[nt] = __builtin_amdgcn_mfma_f32_16x16x32_bf16(aw, bf, accO[nt], 0, 0, 0);
            }
        }
    }

    // ---- endgame: nrm combine across mh through LDS (xs overlay dead)
    __syncthreads();
    if (g == 0) {
        nrm0 += __shfl_xor(nrm0, 16, 64);
        nrm0 += __shfl_xor(nrm0, 32, 64);
        nrm1 += __shfl_xor(nrm1, 16, 64);
        nrm1 += __shfl_xor(nrm1, 32, 64);
        if (lane < 16) {
            u.np[mh][nh * 32 + lane]      = nrm0;
            u.np[mh][nh * 32 + 16 + lane] = nrm1;
        }
    }
    __syncthreads();

    // ---- flush accO (v4 verbatim): rows s = w4*16+q*4+r, cols d = g*32+nt*16+l
    if (SLAB) {
        float* sp = accg + ((size_t)(b * H_ + h) * PBLK + p) * 4096;
        #pragma unroll
        for (int nt = 0; nt < 2; ++nt)
            #pragma unroll
            for (int r = 0; r < 4; ++r)
                sp[(w4 * 16 + q * 4 + r) * 64 + g * 32 + nt * 16 + l] = accO[nt][r];
        if (wv == 0) {
            float v = u.np[0][lane] + u.np[1][lane];
            nrmg[((b * H_ + h) * PBLK + p) * 64 + lane] = v;
        }
    } else {
        float* ag = accg + (size_t)((b * H_ + h) * 64) * 64;
        #pragma unroll
        for (int nt = 0; nt < 2; ++nt)
            #pragma unroll
            for (int r = 0; r < 4; ++r)
                atomicAdd(ag + (w4 * 16 + q * 4 + r) * 64 + g * 32 + nt * 16 + l, accO[nt][r]);
        if (wv == 0) {
            float v = u.np[0][lane] + u.np[1][lane];
            atomicAdd(nrmg + (b * H_ + h) * 64 + lane, v);
        }
    }
}

// ---------------------------------------------------------------------------
__global__ void finalize_big(const float* __restrict__ slab,
                             const float* __restrict__ nslab,
                             float* __restrict__ out) {
    int idx = blockIdx.x * 256 + threadIdx.x;  // 65536
    int bh = idx >> 12, sd = idx & 4095, s = sd >> 6;
    const float* sp = slab  + (size_t)bh * PBLK * 4096 + sd;
    const float* np = nslab + bh * PBLK * 64 + s;
    float acc = 0.f, nn = 0.f;
    #pragma unroll 8
    for (int p = 0; p < PBLK; ++p) { acc += sp[p * 4096]; nn += np[p * 64]; }
    out[idx] = acc / (nn + 1e-5f);
}

__global__ void finalize_small(const uint8_t* __restrict__ wsb, float* __restrict__ out) {
    int idx = blockIdx.x * 256 + threadIdx.x;
    float a = ((const float*)(wsb + ACC_OFF))[idx];
    float n = ((const float*)(wsb + NRM_OFF))[idx / D_];
    out[idx] = a / (n + 1e-5f);
}

// ---------------------------------------------------------------------------
extern "C" void kernel_launch(void* const* d_in, const int* in_sizes, int n_in,
                              void* d_out, int out_size, void* d_ws, size_t ws_size,
                              hipStream_t stream) {
    const float* x           = (const float*)d_in[0];
    const float* W_x         = (const float*)d_in[1];
    const float* b_x         = (const float*)d_in[2];
    const float* W_fx        = (const float*)d_in[3];
    const float* b_fx        = (const float*)d_in[4];
    const float* W_slice     = (const float*)d_in[5];
    const float* b_slice     = (const float*)d_in[6];
    const float* temperature = (const float*)d_in[7];
    float* out = (float*)d_out;
    uint8_t* wsb = (uint8_t*)d_ws;

    int prep_waves = 2 * H_ * C_ + H_;                 // 4104
    prep_kernel<<<dim3((prep_waves + 3) / 4), dim3(256), 0, stream>>>(
        W_x, b_x, W_fx, W_slice, b_slice, temperature, wsb);

    if (ws_size >= (size_t)WS_BIG_END) {
        main_kernel<true><<<dim3(PBLK * H_ * B_), dim3(512), 0, stream>>>(
            x, b_fx, wsb, (float*)(wsb + SLAB_OFF), (float*)(wsb + NSLAB_OFF));
        finalize_big<<<dim3(256), dim3(256), 0, stream>>>(
            (const float*)(wsb + SLAB_OFF), (const float*)(wsb + NSLAB_OFF), out);
    } else {
        hipMemsetAsync(wsb + ACC_OFF, 0, (B_ * H_ * S_ * D_ + B_ * H_ * S_) * 4, stream);
        main_kernel<false><<<dim3(PBLK * H_ * B_), dim3(512), 0, stream>>>(
            x, b_fx, wsb, (float*)(wsb + ACC_OFF), (float*)(wsb + NRM_OFF));
        finalize_small<<<dim3(256), dim3(256), 0, stream>>>(wsb, out);
    }
}

// Round 4
// 652.324 us; speedup vs baseline: 1.2450x; 1.1788x over previous
//
#include <hip/hip_runtime.h>
#include <hip/hip_bf16.h>
#include <cstdint>

// Problem constants
#define B_     2
#define N_     100000
#define C_     256
#define H_     8
#define D_     64
#define S_     64
#define INNER_ 512

#define TILE_T 64
#define NTILES ((N_ + TILE_T - 1) / TILE_T)   // 1563
#define PBLK   16                             // blocks per (b,h); grid = 16*8*2 = 256 blocks = 1/CU

// Workspace layout (bytes)
#define WEFFT_OFF 0                           // bf16 [H][S][C]   = 262144  (pre-scaled by log2e/temp)
#define WFXT_OFF  262144                      // bf16 [H][D][C]   = 262144
#define BIASE_OFF 524288                      // f32  [H][S]      = 2048    (pre-scaled)
#define SLAB_OFF  526336                      // f32 [B*H][PBLK][4096]
#define NSLAB_OFF (SLAB_OFF + B_*H_*PBLK*4096*4)
#define WS_BIG_END (NSLAB_OFF + B_*H_*PBLK*64*4)
#define ACC_OFF   526336
#define NRM_OFF   (ACC_OFF + B_*H_*S_*D_*4)
#define WS_SMALL_END (NRM_OFF + B_*H_*S_*4)

typedef __attribute__((ext_vector_type(8)))  short short8;
typedef __attribute__((ext_vector_type(4)))  float f32x4;

__device__ inline short f2bf(float f) {
    __hip_bfloat16 h = __float2bfloat16(f);
    short s; __builtin_memcpy(&s, &h, 2); return s;
}
__device__ inline uint32_t pk2(float a, float b) {
    __hip_bfloat162 h = __float22bfloat162_rn(float2{a, b});
    uint32_t u; __builtin_memcpy(&u, &h, 4); return u;
}

// ---------------------------------------------------------------------------
// prep: unchanged (v4).
// ---------------------------------------------------------------------------
__global__ void prep_kernel(const float* __restrict__ W_x,
                            const float* __restrict__ b_x,
                            const float* __restrict__ W_fx,
                            const float* __restrict__ W_slice,
                            const float* __restrict__ b_slice,
                            const float* __restrict__ temperature,
                            uint8_t* __restrict__ wsb) {
    int wid  = (blockIdx.x * 256 + threadIdx.x) >> 6;
    int lane = threadIdx.x & 63;
    if (wid < H_ * C_) {
        int h = wid >> 8, k = wid & 255;
        float t = temperature[h]; t = fminf(fmaxf(t, 0.1f), 5.0f);
        float sc = 1.44269504088896f / t;
        const float* wx = W_x + k * INNER_ + h * 64;
        float a = 0.f;
        #pragma unroll 8
        for (int d = 0; d < D_; ++d)
            a = fmaf(wx[d], W_slice[d * 64 + lane], a);
        ((short*)(wsb + WEFFT_OFF))[(h * 64 + lane) * 256 + k] = f2bf(a * sc);
    } else if (wid < 2 * H_ * C_) {
        int j = wid - H_ * C_;
        int h = j >> 8, k = j & 255;
        ((short*)(wsb + WFXT_OFF))[(h * 64 + lane) * 256 + k] =
            f2bf(W_fx[k * INNER_ + h * 64 + lane]);
    } else if (wid < 2 * H_ * C_ + H_) {
        int h = wid - 2 * H_ * C_;
        float t = temperature[h]; t = fminf(fmaxf(t, 0.1f), 5.0f);
        float sc = 1.44269504088896f / t;
        float a = 0.f;
        #pragma unroll 8
        for (int d = 0; d < D_; ++d)
            a = fmaf(b_x[h * 64 + d], W_slice[d * 64 + lane], a);
        ((float*)(wsb + BIASE_OFF))[h * 64 + lane] = (a + b_slice[lane]) * sc;
    }
}

// ---------------------------------------------------------------------------
// main v7 = v6 dataflow at full register budget.
//   32x32 per-wave main-GEMM tile via 2x2 16x16x32 MFMAs (4 independent
//   accumulators); breg[2][8] persistent (64 regs); per-wave A-reads halved
//   vs v4. Roles: g = wv>>2 (0 logits/1 fx), mh = (wv>>1)&1 (token half),
//   nh = wv&1 (col half). Agg roles (w4 = wv&3 s-strip, g d-half) = v4.
//   3 barriers/tile (xs un-unioned from wsl/fsl).
// v7 fix vs v6/v6.1: __launch_bounds__(512,2) — the (512,4)=128-reg cap
//   spilled breg to scratch (round-3: FETCH 1.27 GB = spill re-reads).
//   Persistent need ~150 regs -> needs the 256-reg budget; occupancy is
//   1 block/CU by design. PBLK=16 -> grid 256 = exactly 1 block per CU,
//   no tail, no scheduling rounds. Prefetch in max-overlap slot (after B2):
//   xv regs coexist with acc under the 256-reg budget without spill.
// ---------------------------------------------------------------------------
template<bool SLAB>
__global__ __launch_bounds__(512, 2) void main_kernel(
        const float* __restrict__ x,
        const float* __restrict__ b_fx,
        const uint8_t* __restrict__ wsb,
        float* __restrict__ accg,
        float* __restrict__ nrmg) {
    __shared__ union {
        short xs[TILE_T * 264];               // 33792 B  [tok][k] bf16
        float np[2][64];                      // endgame nrm combine
    } u;
    __shared__ short wsl[S_ * 72];            // 9216 B  [s][tok] bf16
    __shared__ short fsl[D_ * 72];            // 9216 B  [d][tok] bf16
    __shared__ float smB[TILE_T * 2];         // 512 B   [tok][nh] partial sumexp

    const int tid = threadIdx.x;
    const int bid = blockIdx.x;
    // XCD swizzle: 8 h-siblings of each (p,b) group share bid%8 (same XCD)
    const int cc = bid & 7;
    const int h  = (bid >> 3) & 7;
    const int pb = (bid >> 6) * 8 + cc;       // [0, PBLK*B_) = [0,32)
    const int p  = pb & (PBLK - 1);
    const int b  = pb >> 4;                   // pb / PBLK

    const int lane = tid & 63, wv = tid >> 6;
    const int l = lane & 15, q = lane >> 4;
    const int g  = wv >> 2;                   // 0: logits, 1: fx  (also agg d-half)
    const int mh = (wv >> 1) & 1;             // main: token half
    const int nh = wv & 1;                    // main: col half
    const int w4 = wv & 3;                    // agg: s-strip

    // persistent B-frags: 2 col-groups x 8 k-frags (64 regs)
    const short* wT = (const short*)(wsb + (g ? WFXT_OFF : WEFFT_OFF)) + h * (64 * 256);
    short8 breg[2][8];
    #pragma unroll
    for (int j = 0; j < 2; ++j)
        #pragma unroll
        for (int k = 0; k < 8; ++k)
            breg[j][k] = *(const short8*)(wT + (nh * 32 + j * 16 + l) * 256 + k * 32 + q * 8);

    float bias[2];
    {
        const float* bp = g ? (b_fx + h * 64)
                            : ((const float*)(wsb + BIASE_OFF) + h * 64);
        bias[0] = bp[nh * 32 + l];
        bias[1] = bp[nh * 32 + 16 + l];
    }

    const float* xb = x + (size_t)b * ((size_t)N_ * C_);
    f32x4 accO[2] = {};                       // agg out: [16 s][32 d] strip (v4)
    float nrm0 = 0.f, nrm1 = 0.f;             // per-lane norm partials

    // prologue: prefetch first tile into registers
    float4 xv[8];
    {
        const int col = lane * 4;
        #pragma unroll
        for (int j = 0; j < 8; ++j) {
            int gt = p * TILE_T + wv + 8 * j;
            xv[j] = (gt < N_) ? *(const float4*)(xb + (size_t)gt * C_ + col)
                              : float4{0.f, 0.f, 0.f, 0.f};
        }
    }

    #pragma unroll 1
    for (int tile = p; tile < NTILES; tile += PBLK) {
        // ---- pack prefetched tile -> xs. Safe without a barrier: previous
        // iteration's xs reads (main MFMA) completed before previous B3/B4,
        // and agg (between B4 and here) touches only wsl/fsl.
        #pragma unroll
        for (int j = 0; j < 8; ++j) {
            int row = wv + 8 * j;
            uint2 pk = { pk2(xv[j].x, xv[j].y), pk2(xv[j].z, xv[j].w) };
            *(uint2*)(u.xs + row * 264 + lane * 4) = pk;
        }
        __syncthreads();                      // B2: xs ready

        // ---- issue prefetch of NEXT tile (hides under MFMA+softmax+agg)
        {
            int nxt = tile + PBLK;
            if (nxt < NTILES) {
                const int col = lane * 4;
                #pragma unroll
                for (int j = 0; j < 8; ++j) {
                    int gt = nxt * TILE_T + wv + 8 * j;
                    xv[j] = (gt < N_) ? *(const float4*)(xb + (size_t)gt * C_ + col)
                                      : float4{0.f, 0.f, 0.f, 0.f};
                }
            }
        }

        // ---- main MFMA: 32 tok x 32 col per wave, 4 independent accumulators
        f32x4 acc[2][2] = {};
        #pragma unroll
        for (int k = 0; k < 8; ++k) {
            short8 a0 = *(const short8*)(u.xs + (mh * 32 + l) * 264 + k * 32 + q * 8);
            short8 a1 = *(const short8*)(u.xs + (mh * 32 + 16 + l) * 264 + k * 32 + q * 8);
            acc[0][0] = __builtin_amdgcn_mfma_f32_16x16x32_bf16(a0, breg[0][k], acc[0][0], 0, 0, 0);
            acc[0][1] = __builtin_amdgcn_mfma_f32_16x16x32_bf16(a0, breg[1][k], acc[0][1], 0, 0, 0);
            acc[1][0] = __builtin_amdgcn_mfma_f32_16x16x32_bf16(a1, breg[0][k], acc[1][0], 0, 0, 0);
            acc[1][1] = __builtin_amdgcn_mfma_f32_16x16x32_bf16(a1, breg[1][k], acc[1][1], 0, 0, 0);
        }

        if (g == 0) {
            // exp2 (pre-scaled log2 domain) + partial row-sum over this wave's
            // 32 s-cols (pairwise in-thread + 4-step shfl over l)
            #pragma unroll
            for (int i = 0; i < 2; ++i)
                #pragma unroll
                for (int r = 0; r < 4; ++r) {
                    float e0 = __builtin_amdgcn_exp2f(acc[i][0][r] + bias[0]);
                    float e1 = __builtin_amdgcn_exp2f(acc[i][1][r] + bias[1]);
                    acc[i][0][r] = e0;
                    acc[i][1][r] = e1;
                    float s = e0 + e1;
                    s += __shfl_xor(s, 1, 64);
                    s += __shfl_xor(s, 2, 64);
                    s += __shfl_xor(s, 4, 64);
                    s += __shfl_xor(s, 8, 64);
                    if (l == 0) smB[(mh * 32 + i * 16 + q * 4 + r) * 2 + nh] = s;
                }
        } else {
            // fx: add bias, write fsl now (no smB dependency; safe vs agg(t-1)
            // because B2 separates agg reads from these writes)
            #pragma unroll
            for (int i = 0; i < 2; ++i) {
                #pragma unroll
                for (int r = 0; r < 4; ++r) {
                    acc[i][0][r] += bias[0];
                    acc[i][1][r] += bias[1];
                }
                #pragma unroll
                for (int j = 0; j < 2; ++j) {
                    uint2 pk = { pk2(acc[i][j][0], acc[i][j][1]),
                                 pk2(acc[i][j][2], acc[i][j][3]) };
                    *(uint2*)(fsl + (nh * 32 + j * 16 + l) * 72 + mh * 32 + i * 16 + q * 4) = pk;
                }
            }
        }
        __syncthreads();                      // B3: smB (and fsl) ready

        if (g == 0) {
            const int t0 = tile * TILE_T;
            #pragma unroll
            for (int i = 0; i < 2; ++i) {
                const int tb = mh * 32 + i * 16 + q * 4;
                float4 fa = *(const float4*)(smB + tb * 2);
                float4 fb = *(const float4*)(smB + tb * 2 + 4);
                float Ss[4] = { fa.x + fa.y, fa.z + fa.w, fb.x + fb.y, fb.z + fb.w };
                float w0[4], w1[4];
                #pragma unroll
                for (int r = 0; r < 4; ++r) {
                    float f = __builtin_amdgcn_rcpf(Ss[r]);
                    if (t0 + tb + r >= N_) f = 0.f;
                    w0[r] = acc[i][0][r] * f;
                    w1[r] = acc[i][1][r] * f;
                    nrm0 += w0[r];
                    nrm1 += w1[r];
                }
                uint2 p0 = { pk2(w0[0], w0[1]), pk2(w0[2], w0[3]) };
                uint2 p1 = { pk2(w1[0], w1[1]), pk2(w1[2], w1[3]) };
                *(uint2*)(wsl + (nh * 32 + l) * 72      + tb) = p0;
                *(uint2*)(wsl + (nh * 32 + 16 + l) * 72 + tb) = p1;
            }
        }
        __syncthreads();                      // B4: wsl ready

        // ---- agg MFMA (v4 verbatim): wave = (s-strip w4, d-half g)
        #pragma unroll
        for (int kk = 0; kk < 2; ++kk) {
            short8 aw = *(const short8*)(wsl + (w4 * 16 + l) * 72 + kk * 32 + q * 8);
            #pragma unroll
            for (int nt = 0; nt < 2; ++nt) {
                short8 bf = *(const short8*)(fsl + (g * 32 + nt * 16 + l) * 72 + kk * 32 + q * 8);
                accO[nt] = __builtin_amdgcn_mfma_f32_16x16x32_bf16(aw, bf, accO[nt], 0, 0, 0);
            }
        }
    }

    // ---- endgame: nrm combine across mh through LDS (xs overlay dead)
    __syncthreads();
    if (g == 0) {
        nrm0 += __shfl_xor(nrm0, 16, 64);
        nrm0 += __shfl_xor(nrm0, 32, 64);
        nrm1 += __shfl_xor(nrm1, 16, 64);
        nrm1 += __shfl_xor(nrm1, 32, 64);
        if (lane < 16) {
            u.np[mh][nh * 32 + lane]      = nrm0;
            u.np[mh][nh * 32 + 16 + lane] = nrm1;
        }
    }
    __syncthreads();

    // ---- flush accO (v4 verbatim): rows s = w4*16+q*4+r, cols d = g*32+nt*16+l
    if (SLAB) {
        float* sp = accg + ((size_t)(b * H_ + h) * PBLK + p) * 4096;
        #pragma unroll
        for (int nt = 0; nt < 2; ++nt)
            #pragma unroll
            for (int r = 0; r < 4; ++r)
                sp[(w4 * 16 + q * 4 + r) * 64 + g * 32 + nt * 16 + l] = accO[nt][r];
        if (wv == 0) {
            float v = u.np[0][lane] + u.np[1][lane];
            nrmg[((b * H_ + h) * PBLK + p) * 64 + lane] = v;
        }
    } else {
        float* ag = accg + (size_t)((b * H_ + h) * 64) * 64;
        #pragma unroll
        for (int nt = 0; nt < 2; ++nt)
            #pragma unroll
            for (int r = 0; r < 4; ++r)
                atomicAdd(ag + (w4 * 16 + q * 4 + r) * 64 + g * 32 + nt * 16 + l, accO[nt][r]);
        if (wv == 0) {
            float v = u.np[0][lane] + u.np[1][lane];
            atomicAdd(nrmg + (b * H_ + h) * 64 + lane, v);
        }
    }
}

// ---------------------------------------------------------------------------
__global__ void finalize_big(const float* __restrict__ slab,
                             const float* __restrict__ nslab,
                             float* __restrict__ out) {
    int idx = blockIdx.x * 256 + threadIdx.x;  // 65536
    int bh = idx >> 12, sd = idx & 4095, s = sd >> 6;
    const float* sp = slab  + (size_t)bh * PBLK * 4096 + sd;
    const float* np = nslab + bh * PBLK * 64 + s;
    float acc = 0.f, nn = 0.f;
    #pragma unroll 8
    for (int p = 0; p < PBLK; ++p) { acc += sp[p * 4096]; nn += np[p * 64]; }
    out[idx] = acc / (nn + 1e-5f);
}

__global__ void finalize_small(const uint8_t* __restrict__ wsb, float* __restrict__ out) {
    int idx = blockIdx.x * 256 + threadIdx.x;
    float a = ((const float*)(wsb + ACC_OFF))[idx];
    float n = ((const float*)(wsb + NRM_OFF))[idx / D_];
    out[idx] = a / (n + 1e-5f);
}

// ---------------------------------------------------------------------------
extern "C" void kernel_launch(void* const* d_in, const int* in_sizes, int n_in,
                              void* d_out, int out_size, void* d_ws, size_t ws_size,
                              hipStream_t stream) {
    const float* x           = (const float*)d_in[0];
    const float* W_x         = (const float*)d_in[1];
    const float* b_x         = (const float*)d_in[2];
    const float* W_fx        = (const float*)d_in[3];
    const float* b_fx        = (const float*)d_in[4];
    const float* W_slice     = (const float*)d_in[5];
    const float* b_slice     = (const float*)d_in[6];
    const float* temperature = (const float*)d_in[7];
    float* out = (float*)d_out;
    uint8_t* wsb = (uint8_t*)d_ws;

    int prep_waves = 2 * H_ * C_ + H_;                 // 4104
    prep_kernel<<<dim3((prep_waves + 3) / 4), dim3(256), 0, stream>>>(
        W_x, b_x, W_fx, W_slice, b_slice, temperature, wsb);

    if (ws_size >= (size_t)WS_BIG_END) {
        main_kernel<true><<<dim3(PBLK * H_ * B_), dim3(512), 0, stream>>>(
            x, b_fx, wsb, (float*)(wsb + SLAB_OFF), (float*)(wsb + NSLAB_OFF));
        finalize_big<<<dim3(256), dim3(256), 0, stream>>>(
            (const float*)(wsb + SLAB_OFF), (const float*)(wsb + NSLAB_OFF), out);
    } else {
        hipMemsetAsync(wsb + ACC_OFF, 0, (B_ * H_ * S_ * D_ + B_ * H_ * S_) * 4, stream);
        main_kernel<false><<<dim3(PBLK * H_ * B_), dim3(512), 0, stream>>>(
            x, b_fx, wsb, (float*)(wsb + ACC_OFF), (float*)(wsb + NRM_OFF));
        finalize_small<<<dim3(256), dim3(256), 0, stream>>>(wsb, out);
    }
}